// Round 4
// baseline (2228.652 us; speedup 1.0000x reference)
//
#include <hip/hip_runtime.h>
#include <hip/hip_bf16.h>

// FilterModule: 7x MHA fusion pipeline, bf16 MFMA + flash attention v3.
// Flash: 32 q-rows/wave (halved LDS frag traffic), 4-way KV split, LDS P-repack,
// cvt_pk packing, defer-max, setprio. Split-bf16 weight GEMMs unchanged.

typedef __attribute__((ext_vector_type(8))) short short8;
typedef __attribute__((ext_vector_type(4))) float f32x4;
typedef unsigned long long ull;

namespace {
constexpr int NTOK = 4096;
constexpr int EMB  = 1024;
constexpr int QTY  = 512;
}

__device__ __forceinline__ float bf2f(unsigned short u) {
    union { float f; unsigned int i; } x; x.i = ((unsigned int)u) << 16; return x.f;
}
__device__ __forceinline__ unsigned short f2bf(float f) {
    union { float f; unsigned int i; } x; x.f = f;
    unsigned int r = x.i + 0x7fffu + ((x.i >> 16) & 1u);
    return (unsigned short)(r >> 16);
}
__device__ __forceinline__ unsigned int cvt_pk_bf16(float a, float b) {
    unsigned int d;
    asm("v_cvt_pk_bf16_f32 %0, %1, %2" : "=v"(d) : "v"(a), "v"(b));
    return d;
}

#define GLOAD_LDS16(g, l) __builtin_amdgcn_global_load_lds( \
    (const __attribute__((address_space(1))) void*)(g),     \
    (__attribute__((address_space(3))) void*)(l), 16, 0, 0)

// ---------------------------------------------------------------------------
// MFMA GEMM (B^T layout): C[m][n] = alpha*sum_k A[m][k]*B[n][k] (+epilogue).
// 128x128 tile, BK=32, 256 thr. OUTM: 0=f32, 1=bf16, 2=split pair.
template<int SPLITS, int OUTM>
__global__ __launch_bounds__(256)
void gemm_mfma(const unsigned short* __restrict__ Ah, const unsigned short* __restrict__ Al,
               int lda, ull sAz,
               const unsigned short* __restrict__ Bh, const unsigned short* __restrict__ Bl,
               int ldb, ull sBz,
               void* __restrict__ Cp, void* __restrict__ Clp,
               int ldc, ull sCz,
               int K, float alpha, const float* __restrict__ bias,
               const unsigned short* __restrict__ resH, const unsigned short* __restrict__ resL,
               int resMode)
{
    constexpr int TSZ = 128 * 32;
    __shared__ unsigned short lds[(SPLITS == 3 ? 4 : 2) * TSZ];
    const int tid  = threadIdx.x;
    const int brow = blockIdx.y * 128;
    const int bcol = blockIdx.x * 128;
    const ull  z   = blockIdx.z;
    Ah += z * sAz; Bh += z * sBz;
    if constexpr (SPLITS == 3) { Al += z * sAz; Bl += z * sBz; }

    const int lane = tid & 63;
    const int wv = tid >> 6, wr = wv >> 1, wc = wv & 1;
    const int l15 = lane & 15, l4 = lane >> 4;

    f32x4 acc[4][4];
    #pragma unroll
    for (int m = 0; m < 4; ++m)
        #pragma unroll
        for (int n = 0; n < 4; ++n) acc[m][n] = (f32x4){0.f, 0.f, 0.f, 0.f};

    for (int k0 = 0; k0 < K; k0 += 32) {
        #pragma unroll
        for (int i = 0; i < 2; ++i) {
            int idx = tid + i * 256;
            int row = idx >> 2;
            int kc  = (idx & 3) ^ ((row >> 1) & 3);
            GLOAD_LDS16(Ah + (ull)(brow + row) * lda + k0 + kc * 8, &lds[idx * 8]);
            GLOAD_LDS16(Bh + (ull)(bcol + row) * ldb + k0 + kc * 8, &lds[TSZ + idx * 8]);
            if constexpr (SPLITS == 3) {
                GLOAD_LDS16(Al + (ull)(brow + row) * lda + k0 + kc * 8, &lds[2 * TSZ + idx * 8]);
                GLOAD_LDS16(Bl + (ull)(bcol + row) * ldb + k0 + kc * 8, &lds[3 * TSZ + idx * 8]);
            }
        }
        __syncthreads();

        short8 ah[4], bh[4], al2[4], bl2[4];
        #pragma unroll
        for (int m = 0; m < 4; ++m) {
            int rr = wr * 64 + m * 16 + l15;
            int sl = l4 ^ ((rr >> 1) & 3);
            int off = rr * 32 + sl * 8;
            ah[m] = *(const short8*)&lds[off];
            if constexpr (SPLITS == 3) al2[m] = *(const short8*)&lds[2 * TSZ + off];
        }
        #pragma unroll
        for (int n = 0; n < 4; ++n) {
            int rr = wc * 64 + n * 16 + l15;
            int sl = l4 ^ ((rr >> 1) & 3);
            int off = rr * 32 + sl * 8;
            bh[n] = *(const short8*)&lds[TSZ + off];
            if constexpr (SPLITS == 3) bl2[n] = *(const short8*)&lds[3 * TSZ + off];
        }
        #pragma unroll
        for (int m = 0; m < 4; ++m)
            #pragma unroll
            for (int n = 0; n < 4; ++n) {
                acc[m][n] = __builtin_amdgcn_mfma_f32_16x16x32_bf16(ah[m], bh[n], acc[m][n], 0, 0, 0);
                if constexpr (SPLITS == 3) {
                    acc[m][n] = __builtin_amdgcn_mfma_f32_16x16x32_bf16(ah[m], bl2[n], acc[m][n], 0, 0, 0);
                    acc[m][n] = __builtin_amdgcn_mfma_f32_16x16x32_bf16(al2[m], bh[n], acc[m][n], 0, 0, 0);
                }
            }
        __syncthreads();
    }

    float* Cf = (float*)Cp + z * sCz;
    unsigned short* Ch = (unsigned short*)Cp + z * sCz;
    unsigned short* Cl = (unsigned short*)Clp + z * sCz;
    const int rowB = brow + wr * 64 + l4 * 4;
    const int colB = bcol + wc * 64 + l15;
    #pragma unroll
    for (int n = 0; n < 4; ++n) {
        int col = colB + n * 16;
        float bv = bias ? bias[col] : 0.f;
        #pragma unroll
        for (int m = 0; m < 4; ++m) {
            #pragma unroll
            for (int r = 0; r < 4; ++r) {
                int row = rowB + m * 16 + r;
                ull ci = (ull)row * ldc + col;
                float v = acc[m][n][r] * alpha + bv;
                if (resMode == 1)      v += bf2f(resH[ci]) + bf2f(resL[ci]);
                else if (resMode == 2) v *= bf2f(resH[ci]) + bf2f(resL[ci]);
                if constexpr (OUTM == 0)      Cf[ci] = v;
                else if constexpr (OUTM == 1) Ch[ci] = f2bf(v);
                else {
                    unsigned short h = f2bf(v);
                    Ch[ci] = h;
                    Cl[ci] = f2bf(v - bf2f(h));
                }
            }
        }
    }
}

// ---------------------------------------------------------------------------
// Flash attention v3. QKV [4096][3072] bf16; VT [1024][4096] bf16.
// 8 waves x 32 q-rows = 256 q/block; 4-way KV split (1024 kv each); KVB=64.
// Opart: normalized O (bf16) per split; ml: (m,l) f32 pairs.
__global__ __launch_bounds__(512)
void flash_attn(const unsigned short* __restrict__ QKV,
                const unsigned short* __restrict__ VT,
                unsigned short* __restrict__ Opart, float* __restrict__ ml)
{
    constexpr int KVB = 64;
    constexpr int NTILE = 1024 / KVB;            // 16
    __shared__ unsigned short Kt[2][KVB * 256];  // 64 KB
    __shared__ unsigned short Vt[2][256 * KVB];  // 64 KB
    __shared__ unsigned short Pb[8 * 1024];      // 16 KB (per-wave 32q x 32kv)

    const int tid = threadIdx.x;
    const int w = tid >> 6, lane = tid & 63;
    const int l15 = lane & 15, l4 = lane >> 4;
    const int qt = blockIdx.x, sp = blockIdx.y, h = blockIdx.z;
    const int qbase = qt * 256 + w * 32;
    const int kv0 = sp * 1024;
    unsigned short* Pw = &Pb[w * 1024];

    // Q B-fragments (2 q-frags x 8 k-chunks), pre-scaled by 1/16 (exact)
    short8 qreg[2][8];
    #pragma unroll
    for (int qf = 0; qf < 2; ++qf) {
        const unsigned short* qp = QKV + (ull)(qbase + qf * 16 + l15) * 3072 + h * 256;
        #pragma unroll
        for (int c = 0; c < 8; ++c) {
            short8 x = *(const short8*)&qp[c * 32 + l4 * 8];
            #pragma unroll
            for (int j = 0; j < 8; ++j)
                x[j] = (short)f2bf(bf2f((unsigned short)x[j]) * 0.0625f);
            qreg[qf][c] = x;
        }
    }

    f32x4 oacc[2][16];
    #pragma unroll
    for (int qf = 0; qf < 2; ++qf)
        #pragma unroll
        for (int dn = 0; dn < 16; ++dn) oacc[qf][dn] = (f32x4){0.f, 0.f, 0.f, 0.f};
    float m_r[2] = { -1e30f, -1e30f }, l_r[2] = { 0.f, 0.f };

    auto stage = [&](int t, int buf) {
        int base = kv0 + t * KVB;
        #pragma unroll
        for (int i = 0; i < 4; ++i) {       // K tile: 64 rows x 32 chunks
            int s = tid + i * 512;
            int r = s >> 5, c = s & 31;
            int c0 = c ^ (r & 7);
            GLOAD_LDS16(QKV + (ull)(base + r) * 3072 + 1024 + h * 256 + c0 * 8,
                        &Kt[buf][s * 8]);
        }
        #pragma unroll
        for (int i = 0; i < 4; ++i) {       // V^T tile: 256 rows x 8 chunks
            int s = tid + i * 512;
            int r = s >> 3, c = s & 7;
            int c0 = c ^ (r & 7);
            GLOAD_LDS16(VT + (ull)(h * 256 + r) * 4096 + base + c0 * 8,
                        &Vt[buf][s * 8]);
        }
    };

    stage(0, 0);
    for (int t = 0; t < NTILE; ++t) {
        if (t + 1 < NTILE) {
            stage(t + 1, (t + 1) & 1);
            asm volatile("s_waitcnt vmcnt(8)");
        } else {
            asm volatile("s_waitcnt vmcnt(0)");
        }
        __builtin_amdgcn_s_barrier();

        const unsigned short* Kb = Kt[t & 1];
        const unsigned short* Vb = Vt[t & 1];

        // QK^T (swapped): sacc[qf][fk], lane: q=l15, kv=fk*16+l4*4+r
        f32x4 sacc[2][4];
        #pragma unroll
        for (int qf = 0; qf < 2; ++qf)
            #pragma unroll
            for (int fk = 0; fk < 4; ++fk) sacc[qf][fk] = (f32x4){0.f, 0.f, 0.f, 0.f};

        __builtin_amdgcn_s_setprio(1);
        #pragma unroll
        for (int c = 0; c < 8; ++c) {
            short8 kf[4];
            #pragma unroll
            for (int fk = 0; fk < 4; ++fk) {
                int r = fk * 16 + l15;
                int ch = (4 * c + l4) ^ (r & 7);
                kf[fk] = *(const short8*)&Kb[r * 256 + ch * 8];
            }
            #pragma unroll
            for (int fk = 0; fk < 4; ++fk) {
                sacc[0][fk] = __builtin_amdgcn_mfma_f32_16x16x32_bf16(kf[fk], qreg[0][c], sacc[0][fk], 0, 0, 0);
                sacc[1][fk] = __builtin_amdgcn_mfma_f32_16x16x32_bf16(kf[fk], qreg[1][c], sacc[1][fk], 0, 0, 0);
            }
        }
        __builtin_amdgcn_s_setprio(0);

        // online softmax per q-frag (q = l15 domain; reduce over l4 groups)
        float p[2][16];
        #pragma unroll
        for (int qf = 0; qf < 2; ++qf) {
            float tm = sacc[qf][0][0];
            #pragma unroll
            for (int fk = 0; fk < 4; ++fk)
                #pragma unroll
                for (int rr = 0; rr < 4; ++rr) tm = fmaxf(tm, sacc[qf][fk][rr]);
            tm = fmaxf(tm, __shfl_xor(tm, 16));
            tm = fmaxf(tm, __shfl_xor(tm, 32));

            // defer-max: rescale only when tile max exceeds running max + THR
            if (!__all(tm <= m_r[qf] + 5.545f)) {
                float mnew = fmaxf(m_r[qf], tm);
                float corr = __expf(m_r[qf] - mnew);
                float c4[4];
                #pragma unroll
                for (int r = 0; r < 4; ++r) c4[r] = __shfl(corr, l4 * 4 + r);
                #pragma unroll
                for (int dn = 0; dn < 16; ++dn)
                    #pragma unroll
                    for (int r = 0; r < 4; ++r) oacc[qf][dn][r] *= c4[r];
                l_r[qf] *= corr;
                m_r[qf] = mnew;
            }

            float ls = 0.f;
            #pragma unroll
            for (int i = 0; i < 16; ++i) {
                float e = __expf(sacc[qf][i >> 2][i & 3] - m_r[qf]);
                p[qf][i] = e; ls += e;
            }
            ls += __shfl_xor(ls, 16);
            ls += __shfl_xor(ls, 32);
            l_r[qf] += ls;
        }

        // PV per 32-kv chunk: LDS round-trip repack -> A-frags, then MFMA
        #pragma unroll
        for (int kvc = 0; kvc < 2; ++kvc) {
            #pragma unroll
            for (int qf = 0; qf < 2; ++qf)
                #pragma unroll
                for (int fh = 0; fh < 2; ++fh) {
                    int fk = kvc * 2 + fh;
                    uint2 wv;
                    wv.x = cvt_pk_bf16(p[qf][fk * 4 + 0], p[qf][fk * 4 + 1]);
                    wv.y = cvt_pk_bf16(p[qf][fk * 4 + 2], p[qf][fk * 4 + 3]);
                    *(uint2*)&Pw[(qf * 16 + l15) * 32 + fh * 16 + l4 * 4] = wv;
                }
            short8 pa0 = *(const short8*)&Pw[l15 * 32 + l4 * 8];
            short8 pa1 = *(const short8*)&Pw[(16 + l15) * 32 + l4 * 8];

            __builtin_amdgcn_s_setprio(1);
            #pragma unroll
            for (int dn = 0; dn < 16; ++dn) {
                int row = dn * 16 + l15;
                int ch = (kvc * 4 + l4) ^ (row & 7);
                short8 vf = *(const short8*)&Vb[row * 64 + ch * 8];
                oacc[0][dn] = __builtin_amdgcn_mfma_f32_16x16x32_bf16(pa0, vf, oacc[0][dn], 0, 0, 0);
                oacc[1][dn] = __builtin_amdgcn_mfma_f32_16x16x32_bf16(pa1, vf, oacc[1][dn], 0, 0, 0);
            }
            __builtin_amdgcn_s_setprio(0);
        }
        __builtin_amdgcn_s_barrier();
    }

    // epilogue: store normalized O (bf16) + (m,l)
    unsigned short* Ob = Opart + (ull)(sp * 4 + h) * NTOK * 256;
    #pragma unroll
    for (int qf = 0; qf < 2; ++qf) {
        float inv = 1.f / l_r[qf];
        float c4[4];
        #pragma unroll
        for (int r = 0; r < 4; ++r) c4[r] = __shfl(inv, l4 * 4 + r);
        #pragma unroll
        for (int dn = 0; dn < 16; ++dn) {
            int d = dn * 16 + l15;
            #pragma unroll
            for (int r = 0; r < 4; ++r) {
                int q = qbase + qf * 16 + l4 * 4 + r;
                Ob[(ull)q * 256 + d] = f2bf(oacc[qf][dn][r] * c4[r]);
            }
        }
        if (l4 == 0) {
            float2* mlp = (float2*)ml + (ull)(sp * 4 + h) * NTOK + qbase + qf * 16 + l15;
            *mlp = make_float2(m_r[qf], l_r[qf]);
        }
    }
}

// ---------------------------------------------------------------------------
// merge 4 KV-split partials -> att split pair. block = one q row (4h x 256d).
__global__ __launch_bounds__(256)
void flash_combine(const unsigned short* __restrict__ Opart, const float* __restrict__ ml,
                   unsigned short* __restrict__ attH, unsigned short* __restrict__ attL)
{
    const int q = blockIdx.x;
    const int t = threadIdx.x;
    const int h = t >> 6, d4 = (t & 63) * 4;

    float2 m4[4]; float ms = -1e30f;
    #pragma unroll
    for (int s = 0; s < 4; ++s) {
        m4[s] = ((const float2*)ml)[(ull)(s * 4 + h) * NTOK + q];
        ms = fmaxf(ms, m4[s].x);
    }
    float wt[4], denom = 0.f;
    #pragma unroll
    for (int s = 0; s < 4; ++s) {
        wt[s] = __expf(m4[s].x - ms) * m4[s].y;
        denom += wt[s];
    }
    float inv = 1.f / denom;
    float acc[4] = { 0.f, 0.f, 0.f, 0.f };
    #pragma unroll
    for (int s = 0; s < 4; ++s) {
        ushort4 o = *(const ushort4*)&Opart[((ull)(s * 4 + h) * NTOK + q) * 256 + d4];
        acc[0] += wt[s] * bf2f(o.x); acc[1] += wt[s] * bf2f(o.y);
        acc[2] += wt[s] * bf2f(o.z); acc[3] += wt[s] * bf2f(o.w);
    }
    ull ai = (ull)q * EMB + h * 256 + d4;
    ushort4 ho, lo;
    float v0 = acc[0] * inv, v1 = acc[1] * inv, v2 = acc[2] * inv, v3 = acc[3] * inv;
    ho.x = f2bf(v0); lo.x = f2bf(v0 - bf2f(ho.x));
    ho.y = f2bf(v1); lo.y = f2bf(v1 - bf2f(ho.y));
    ho.z = f2bf(v2); lo.z = f2bf(v2 - bf2f(ho.z));
    ho.w = f2bf(v3); lo.w = f2bf(v3 - bf2f(ho.w));
    *(ushort4*)&attH[ai] = ho;
    *(ushort4*)&attL[ai] = lo;
}

// ---------------------------------------------------------------------------
template<bool F32IN>
__global__ __launch_bounds__(256)
void l2norm_rows(const float* __restrict__ inF, const unsigned short* __restrict__ inH,
                 const unsigned short* __restrict__ inL,
                 unsigned short* __restrict__ oH, unsigned short* __restrict__ oL)
{
    const ull row = blockIdx.x;
    const int t = threadIdx.x;
    const int lane = t & 63, wid = t >> 6;
    __shared__ float red[4];

    float v[4];
    if constexpr (F32IN) {
        float4 x = *(const float4*)&inF[row * EMB + t * 4];
        v[0] = x.x; v[1] = x.y; v[2] = x.z; v[3] = x.w;
    } else {
        ushort4 hh = *(const ushort4*)&inH[row * EMB + t * 4];
        ushort4 ll = *(const ushort4*)&inL[row * EMB + t * 4];
        v[0] = bf2f(hh.x) + bf2f(ll.x); v[1] = bf2f(hh.y) + bf2f(ll.y);
        v[2] = bf2f(hh.z) + bf2f(ll.z); v[3] = bf2f(hh.w) + bf2f(ll.w);
    }
    float ss = v[0] * v[0] + v[1] * v[1] + v[2] * v[2] + v[3] * v[3];
    #pragma unroll
    for (int o = 32; o > 0; o >>= 1) ss += __shfl_down(ss, o);
    if (lane == 0) red[wid] = ss;
    __syncthreads();
    ss = red[0] + red[1] + red[2] + red[3];

    float inv = 1.f / fmaxf(sqrtf(ss), 1e-8f);
    ushort4 ho, lo;
    float s0 = v[0] * inv, s1 = v[1] * inv, s2 = v[2] * inv, s3 = v[3] * inv;
    ho.x = f2bf(s0); lo.x = f2bf(s0 - bf2f(ho.x));
    ho.y = f2bf(s1); lo.y = f2bf(s1 - bf2f(ho.y));
    ho.z = f2bf(s2); lo.z = f2bf(s2 - bf2f(ho.z));
    ho.w = f2bf(s3); lo.w = f2bf(s3 - bf2f(ho.w));
    *(ushort4*)&oH[row * EMB + t * 4] = ho;
    *(ushort4*)&oL[row * EMB + t * 4] = lo;
}

__global__ __launch_bounds__(256)
void add_pos_pair(const float* __restrict__ in, const float* __restrict__ pos,
                  unsigned short* __restrict__ oH, unsigned short* __restrict__ oL)
{
    ull i = ((ull)blockIdx.x * 256 + threadIdx.x) * 4;
    float4 a = *(const float4*)&in[i];
    float4 p = *(const float4*)&pos[(int)(i & (EMB - 1))];
    float w[4] = { a.x + p.x, a.y + p.y, a.z + p.z, a.w + p.w };
    ushort4 ho, lo;
    ho.x = f2bf(w[0]); lo.x = f2bf(w[0] - bf2f(ho.x));
    ho.y = f2bf(w[1]); lo.y = f2bf(w[1] - bf2f(ho.y));
    ho.z = f2bf(w[2]); lo.z = f2bf(w[2] - bf2f(ho.z));
    ho.w = f2bf(w[3]); lo.w = f2bf(w[3] - bf2f(ho.w));
    *(ushort4*)&oH[i] = ho;
    *(ushort4*)&oL[i] = lo;
}

__global__ __launch_bounds__(256)
void split_pair(const float* __restrict__ in, unsigned short* __restrict__ oH,
                unsigned short* __restrict__ oL)
{
    ull i = ((ull)blockIdx.x * 256 + threadIdx.x) * 4;
    float4 a = *(const float4*)&in[i];
    float w[4] = { a.x, a.y, a.z, a.w };
    ushort4 ho, lo;
    ho.x = f2bf(w[0]); lo.x = f2bf(w[0] - bf2f(ho.x));
    ho.y = f2bf(w[1]); lo.y = f2bf(w[1] - bf2f(ho.y));
    ho.z = f2bf(w[2]); lo.z = f2bf(w[2] - bf2f(ho.z));
    ho.w = f2bf(w[3]); lo.w = f2bf(w[3] - bf2f(ho.w));
    *(ushort4*)&oH[i] = ho;
    *(ushort4*)&oL[i] = lo;
}

// transpose bf16 [4096][ld] block cols -> out [1024][4096]
__global__ __launch_bounds__(256)
void transpose_bf16(const unsigned short* __restrict__ in, int ld,
                    unsigned short* __restrict__ out) {
    __shared__ unsigned short tile[64][65];
    const int bx = blockIdx.x * 64;
    const int by = blockIdx.y * 64;
    const int t = threadIdx.x;
    #pragma unroll
    for (int i = 0; i < 16; ++i) {
        int idx = i * 256 + t;
        int r = idx >> 6, c = idx & 63;
        tile[r][c] = in[(ull)(by + r) * ld + bx + c];
    }
    __syncthreads();
    #pragma unroll
    for (int i = 0; i < 16; ++i) {
        int idx = i * 256 + t;
        int r = idx >> 6, c = idx & 63;
        out[(ull)(bx + r) * 4096 + by + c] = tile[c][r];
    }
}

// ---------------------------------------------------------------------------
namespace {

template<int S, int O>
inline void G(dim3 grid,
              const unsigned short* Ah, const unsigned short* Al, int lda, ull sAz,
              const unsigned short* Bh, const unsigned short* Bl, int ldb, ull sBz,
              void* Ch, void* Cl, int ldc, ull sCz,
              int K, float alpha, const float* bias,
              const unsigned short* rh, const unsigned short* rl, int rm, hipStream_t st)
{
    gemm_mfma<S, O><<<grid, dim3(256), 0, st>>>(Ah, Al, lda, sAz, Bh, Bl, ldb, sBz,
                                                Ch, Cl, ldc, sCz, K, alpha, bias, rh, rl, rm);
}

struct Bufs {
    unsigned short *Ph[6], *Pl[6];
    unsigned short *ATTh, *ATTl, *QKV, *VT, *Wih, *Wil, *Woh, *Wol, *Opart;
    float *ml;
};

void run_mha(const unsigned short* qh, const unsigned short* ql,
             const unsigned short* kh, const unsigned short* kl,
             const float* in_w, const float* in_b,
             const float* out_w, const float* out_b,
             unsigned short* dsth, unsigned short* dstl,
             const unsigned short* resh, const unsigned short* resl, int resMode,
             const Bufs& B, bool convW, hipStream_t s)
{
    const ull EE = (ull)EMB * EMB;
    if (convW) {
        split_pair<<<3 * EE / 1024, 256, 0, s>>>(in_w, B.Wih, B.Wil);
        split_pair<<<EE / 1024, 256, 0, s>>>(out_w, B.Woh, B.Wol);
    }
    // Q proj -> QKV[:, 0:1024]; fused KV proj -> QKV[:, 1024:3072]
    G<3, 1>(dim3(8, 32), qh, ql, EMB, 0, B.Wih, B.Wil, EMB, 0,
            B.QKV, nullptr, 3072, 0, EMB, 1.f, in_b, nullptr, nullptr, 0, s);
    G<3, 1>(dim3(16, 32), kh, kl, EMB, 0, B.Wih + EE, B.Wil + EE, EMB, 0,
            B.QKV + 1024, nullptr, 3072, 0, EMB, 1.f, in_b + EMB, nullptr, nullptr, 0, s);
    transpose_bf16<<<dim3(16, 64), 256, 0, s>>>(B.QKV + 2048, 3072, B.VT);

    flash_attn<<<dim3(16, 4, 4), 512, 0, s>>>(B.QKV, B.VT, B.Opart, B.ml);
    flash_combine<<<NTOK, 256, 0, s>>>(B.Opart, B.ml, B.ATTh, B.ATTl);

    G<3, 2>(dim3(EMB / 128, NTOK / 128), B.ATTh, B.ATTl, EMB, 0, B.Woh, B.Wol, EMB, 0,
            dsth, dstl, EMB, 0, EMB, 1.f, out_b, resh, resl, resMode, s);
}

} // namespace

extern "C" void kernel_launch(void* const* d_in, const int* in_sizes, int n_in,
                              void* d_out, int out_size, void* d_ws, size_t ws_size,
                              hipStream_t stream) {
    const float* local_feat  = (const float*)d_in[0];
    const float* global_feat = (const float*)d_in[1];
    const float* text_feat   = (const float*)d_in[2];
    const float* pos_l       = (const float*)d_in[3];
    const float* pos_g       = (const float*)d_in[4];
    const float* fc_w        = (const float*)d_in[5];
    const float* fc_b        = (const float*)d_in[6];
    const float* lg_in_w     = (const float*)d_in[7];
    const float* lg_in_b     = (const float*)d_in[8];
    const float* lg_out_w    = (const float*)d_in[9];
    const float* lg_out_b    = (const float*)d_in[10];
    const float* vt_in_w     = (const float*)d_in[11];
    const float* vt_in_b     = (const float*)d_in[12];
    const float* vt_out_w    = (const float*)d_in[13];
    const float* vt_out_b    = (const float*)d_in[14];
    const float* ml_in_w     = (const float*)d_in[15];
    const float* ml_in_b     = (const float*)d_in[16];
    const float* ml_out_w    = (const float*)d_in[17];
    const float* ml_out_b    = (const float*)d_in[18];
    float* out = (float*)d_out;

    const ull TE = (ull)NTOK * EMB;
    unsigned short* w = (unsigned short*)d_ws;
    Bufs B;
    for (int i = 0; i < 6; ++i) { B.Ph[i] = w + (2 * i) * TE; B.Pl[i] = w + (2 * i + 1) * TE; }
    B.ATTh = w + 12 * TE; B.ATTl = w + 13 * TE;
    B.QKV  = w + 14 * TE;               // 3 TE
    B.VT   = w + 17 * TE;               // 1 TE
    B.Opart = w + 18 * TE;              // 4 TE (bf16, 4 splits x 4 heads)
    B.ml    = (float*)(w + 22 * TE);    // 512 KB
    B.Wih = w + 26 * TE; B.Wil = B.Wih + 3 * (ull)EMB * EMB;
    B.Woh = B.Wil + 3 * (ull)EMB * EMB; B.Wol = B.Woh + (ull)EMB * EMB;

    add_pos_pair<<<TE / 1024, 256, 0, stream>>>(local_feat, pos_l, B.Ph[0], B.Pl[0]);
    add_pos_pair<<<TE / 1024, 256, 0, stream>>>(global_feat, pos_g, B.Ph[1], B.Pl[1]);

    // tf = text @ fc_w^T + fc_b -> P2 (text split staged in ATT pair)
    split_pair<<<TE / 1024, 256, 0, stream>>>(text_feat, B.ATTh, B.ATTl);
    split_pair<<<(ull)EMB * EMB / 1024, 256, 0, stream>>>(fc_w, B.Wih, B.Wil);
    G<3, 2>(dim3(EMB / 128, NTOK / 128), B.ATTh, B.ATTl, EMB, 0, B.Wih, B.Wil, EMB, 0,
            B.Ph[2], B.Pl[2], EMB, 0, EMB, 1.f, fc_b, nullptr, nullptr, 0, stream);

    run_mha(B.Ph[0], B.Pl[0], B.Ph[1], B.Pl[1], lg_in_w, lg_in_b, lg_out_w, lg_out_b,
            B.Ph[3], B.Pl[3], B.Ph[0], B.Pl[0], 1, B, true, stream);
    run_mha(B.Ph[2], B.Pl[2], B.Ph[0], B.Pl[0], vt_in_w, vt_in_b, vt_out_w, vt_out_b,
            B.Ph[4], B.Pl[4], B.Ph[0], B.Pl[0], 1, B, true, stream);
    run_mha(B.Ph[2], B.Pl[2], B.Ph[1], B.Pl[1], vt_in_w, vt_in_b, vt_out_w, vt_out_b,
            B.Ph[5], B.Pl[5], B.Ph[2], B.Pl[2], 1, B, false, stream);
    run_mha(B.Ph[3], B.Pl[3], B.Ph[5], B.Pl[5], ml_in_w, ml_in_b, ml_out_w, ml_out_b,
            B.Ph[0], B.Pl[0], nullptr, nullptr, 0, B, true, stream);
    run_mha(B.Ph[4], B.Pl[4], B.Ph[3], B.Pl[3], ml_in_w, ml_in_b, ml_out_w, ml_out_b,
            B.Ph[1], B.Pl[1], nullptr, nullptr, 0, B, false, stream);
    run_mha(B.Ph[1], B.Pl[1], B.Ph[0], B.Pl[0], ml_in_w, ml_in_b, ml_out_w, ml_out_b,
            B.Ph[3], B.Pl[3], nullptr, nullptr, 0, B, false, stream);
    run_mha(B.Ph[2], B.Pl[2], B.Ph[3], B.Pl[3], ml_in_w, ml_in_b, ml_out_w, ml_out_b,
            B.Ph[4], B.Pl[4], B.Ph[2], B.Pl[2], 2, B, false, stream);

    l2norm_rows<false><<<NTOK, 256, 0, stream>>>(nullptr, B.Ph[4], B.Pl[4], B.Ph[4], B.Pl[4]);
    l2norm_rows<true ><<<NTOK, 256, 0, stream>>>(local_feat, nullptr, nullptr, B.Ph[5], B.Pl[5]);

    G<3, 0>(dim3(QTY / 128, QTY / 128, 8),
            B.Ph[4], B.Pl[4], EMB, (ull)QTY * EMB,
            B.Ph[5], B.Pl[5], EMB, (ull)QTY * EMB,
            out, nullptr, QTY, (ull)QTY * QTY,
            EMB, 1.f, nullptr, nullptr, nullptr, 0, stream);
}

// Round 5
// 2162.601 us; speedup vs baseline: 1.0305x; 1.0305x over previous
//
#include <hip/hip_runtime.h>
#include <hip/hip_bf16.h>

// FilterModule: 7x MHA fusion pipeline, bf16 MFMA + flash attention v4.
// v4 = v3 geometry (32 q/wave, 4-way KV split) + VGPR cap 256 (no spill),
// in-place exp (reg reduction), XOR-swizzled P-repack (conflict-free).

typedef __attribute__((ext_vector_type(8))) short short8;
typedef __attribute__((ext_vector_type(4))) float f32x4;
typedef unsigned long long ull;

namespace {
constexpr int NTOK = 4096;
constexpr int EMB  = 1024;
constexpr int QTY  = 512;
}

__device__ __forceinline__ float bf2f(unsigned short u) {
    union { float f; unsigned int i; } x; x.i = ((unsigned int)u) << 16; return x.f;
}
__device__ __forceinline__ unsigned short f2bf(float f) {
    union { float f; unsigned int i; } x; x.f = f;
    unsigned int r = x.i + 0x7fffu + ((x.i >> 16) & 1u);
    return (unsigned short)(r >> 16);
}
__device__ __forceinline__ unsigned int cvt_pk_bf16(float a, float b) {
    unsigned int d;
    asm("v_cvt_pk_bf16_f32 %0, %1, %2" : "=v"(d) : "v"(a), "v"(b));
    return d;
}

#define GLOAD_LDS16(g, l) __builtin_amdgcn_global_load_lds( \
    (const __attribute__((address_space(1))) void*)(g),     \
    (__attribute__((address_space(3))) void*)(l), 16, 0, 0)

// ---------------------------------------------------------------------------
// MFMA GEMM (B^T layout): C[m][n] = alpha*sum_k A[m][k]*B[n][k] (+epilogue).
// 128x128 tile, BK=32, 256 thr. OUTM: 0=f32, 1=bf16, 2=split pair.
template<int SPLITS, int OUTM>
__global__ __launch_bounds__(256)
void gemm_mfma(const unsigned short* __restrict__ Ah, const unsigned short* __restrict__ Al,
               int lda, ull sAz,
               const unsigned short* __restrict__ Bh, const unsigned short* __restrict__ Bl,
               int ldb, ull sBz,
               void* __restrict__ Cp, void* __restrict__ Clp,
               int ldc, ull sCz,
               int K, float alpha, const float* __restrict__ bias,
               const unsigned short* __restrict__ resH, const unsigned short* __restrict__ resL,
               int resMode)
{
    constexpr int TSZ = 128 * 32;
    __shared__ unsigned short lds[(SPLITS == 3 ? 4 : 2) * TSZ];
    const int tid  = threadIdx.x;
    const int brow = blockIdx.y * 128;
    const int bcol = blockIdx.x * 128;
    const ull  z   = blockIdx.z;
    Ah += z * sAz; Bh += z * sBz;
    if constexpr (SPLITS == 3) { Al += z * sAz; Bl += z * sBz; }

    const int lane = tid & 63;
    const int wv = tid >> 6, wr = wv >> 1, wc = wv & 1;
    const int l15 = lane & 15, l4 = lane >> 4;

    f32x4 acc[4][4];
    #pragma unroll
    for (int m = 0; m < 4; ++m)
        #pragma unroll
        for (int n = 0; n < 4; ++n) acc[m][n] = (f32x4){0.f, 0.f, 0.f, 0.f};

    for (int k0 = 0; k0 < K; k0 += 32) {
        #pragma unroll
        for (int i = 0; i < 2; ++i) {
            int idx = tid + i * 256;
            int row = idx >> 2;
            int kc  = (idx & 3) ^ ((row >> 1) & 3);
            GLOAD_LDS16(Ah + (ull)(brow + row) * lda + k0 + kc * 8, &lds[idx * 8]);
            GLOAD_LDS16(Bh + (ull)(bcol + row) * ldb + k0 + kc * 8, &lds[TSZ + idx * 8]);
            if constexpr (SPLITS == 3) {
                GLOAD_LDS16(Al + (ull)(brow + row) * lda + k0 + kc * 8, &lds[2 * TSZ + idx * 8]);
                GLOAD_LDS16(Bl + (ull)(bcol + row) * ldb + k0 + kc * 8, &lds[3 * TSZ + idx * 8]);
            }
        }
        __syncthreads();

        short8 ah[4], bh[4], al2[4], bl2[4];
        #pragma unroll
        for (int m = 0; m < 4; ++m) {
            int rr = wr * 64 + m * 16 + l15;
            int sl = l4 ^ ((rr >> 1) & 3);
            int off = rr * 32 + sl * 8;
            ah[m] = *(const short8*)&lds[off];
            if constexpr (SPLITS == 3) al2[m] = *(const short8*)&lds[2 * TSZ + off];
        }
        #pragma unroll
        for (int n = 0; n < 4; ++n) {
            int rr = wc * 64 + n * 16 + l15;
            int sl = l4 ^ ((rr >> 1) & 3);
            int off = rr * 32 + sl * 8;
            bh[n] = *(const short8*)&lds[TSZ + off];
            if constexpr (SPLITS == 3) bl2[n] = *(const short8*)&lds[3 * TSZ + off];
        }
        #pragma unroll
        for (int m = 0; m < 4; ++m)
            #pragma unroll
            for (int n = 0; n < 4; ++n) {
                acc[m][n] = __builtin_amdgcn_mfma_f32_16x16x32_bf16(ah[m], bh[n], acc[m][n], 0, 0, 0);
                if constexpr (SPLITS == 3) {
                    acc[m][n] = __builtin_amdgcn_mfma_f32_16x16x32_bf16(ah[m], bl2[n], acc[m][n], 0, 0, 0);
                    acc[m][n] = __builtin_amdgcn_mfma_f32_16x16x32_bf16(al2[m], bh[n], acc[m][n], 0, 0, 0);
                }
            }
        __syncthreads();
    }

    float* Cf = (float*)Cp + z * sCz;
    unsigned short* Ch = (unsigned short*)Cp + z * sCz;
    unsigned short* Cl = (unsigned short*)Clp + z * sCz;
    const int rowB = brow + wr * 64 + l4 * 4;
    const int colB = bcol + wc * 64 + l15;
    #pragma unroll
    for (int n = 0; n < 4; ++n) {
        int col = colB + n * 16;
        float bv = bias ? bias[col] : 0.f;
        #pragma unroll
        for (int m = 0; m < 4; ++m) {
            #pragma unroll
            for (int r = 0; r < 4; ++r) {
                int row = rowB + m * 16 + r;
                ull ci = (ull)row * ldc + col;
                float v = acc[m][n][r] * alpha + bv;
                if (resMode == 1)      v += bf2f(resH[ci]) + bf2f(resL[ci]);
                else if (resMode == 2) v *= bf2f(resH[ci]) + bf2f(resL[ci]);
                if constexpr (OUTM == 0)      Cf[ci] = v;
                else if constexpr (OUTM == 1) Ch[ci] = f2bf(v);
                else {
                    unsigned short h = f2bf(v);
                    Ch[ci] = h;
                    Cl[ci] = f2bf(v - bf2f(h));
                }
            }
        }
    }
}

// ---------------------------------------------------------------------------
// Flash attention v4. QKV [4096][3072] bf16; VT [1024][4096] bf16.
// 8 waves x 32 q-rows = 256 q/block; 4-way KV split (1024 kv each); KVB=64.
// __launch_bounds__(512,2): 2 waves/SIMD -> VGPR cap 256 (prevents R4's spill).
__global__ __launch_bounds__(512, 2)
void flash_attn(const unsigned short* __restrict__ QKV,
                const unsigned short* __restrict__ VT,
                unsigned short* __restrict__ Opart, float* __restrict__ ml)
{
    constexpr int KVB = 64;
    constexpr int NTILE = 1024 / KVB;            // 16
    __shared__ unsigned short Kt[2][KVB * 256];  // 64 KB
    __shared__ unsigned short Vt[2][256 * KVB];  // 64 KB
    __shared__ unsigned short Pb[8 * 1024];      // 16 KB (per-wave 32q x 32kv)

    const int tid = threadIdx.x;
    const int w = tid >> 6, lane = tid & 63;
    const int l15 = lane & 15, l4 = lane >> 4;
    const int qt = blockIdx.x, sp = blockIdx.y, h = blockIdx.z;
    const int qbase = qt * 256 + w * 32;
    const int kv0 = sp * 1024;
    unsigned short* Pw = &Pb[w * 1024];
    const int pswz = (l15 & 3) * 8;              // XOR swizzle, 8-short granular

    // Q B-fragments (2 q-frags x 8 k-chunks), pre-scaled by 1/16 (exact)
    short8 qreg[2][8];
    #pragma unroll
    for (int qf = 0; qf < 2; ++qf) {
        const unsigned short* qp = QKV + (ull)(qbase + qf * 16 + l15) * 3072 + h * 256;
        #pragma unroll
        for (int c = 0; c < 8; ++c) {
            short8 x = *(const short8*)&qp[c * 32 + l4 * 8];
            #pragma unroll
            for (int j = 0; j < 8; ++j)
                x[j] = (short)f2bf(bf2f((unsigned short)x[j]) * 0.0625f);
            qreg[qf][c] = x;
        }
    }

    f32x4 oacc[2][16];
    #pragma unroll
    for (int qf = 0; qf < 2; ++qf)
        #pragma unroll
        for (int dn = 0; dn < 16; ++dn) oacc[qf][dn] = (f32x4){0.f, 0.f, 0.f, 0.f};
    float m_r[2] = { -1e30f, -1e30f }, l_r[2] = { 0.f, 0.f };

    auto stage = [&](int t, int buf) {
        int base = kv0 + t * KVB;
        #pragma unroll
        for (int i = 0; i < 4; ++i) {       // K tile: 64 rows x 32 chunks
            int s = tid + i * 512;
            int r = s >> 5, c = s & 31;
            int c0 = c ^ (r & 7);
            GLOAD_LDS16(QKV + (ull)(base + r) * 3072 + 1024 + h * 256 + c0 * 8,
                        &Kt[buf][s * 8]);
        }
        #pragma unroll
        for (int i = 0; i < 4; ++i) {       // V^T tile: 256 rows x 8 chunks
            int s = tid + i * 512;
            int r = s >> 3, c = s & 7;
            int c0 = c ^ (r & 7);
            GLOAD_LDS16(VT + (ull)(h * 256 + r) * 4096 + base + c0 * 8,
                        &Vt[buf][s * 8]);
        }
    };

    stage(0, 0);
    for (int t = 0; t < NTILE; ++t) {
        if (t + 1 < NTILE) {
            stage(t + 1, (t + 1) & 1);
            asm volatile("s_waitcnt vmcnt(8)");
        } else {
            asm volatile("s_waitcnt vmcnt(0)");
        }
        __builtin_amdgcn_s_barrier();

        const unsigned short* Kb = Kt[t & 1];
        const unsigned short* Vb = Vt[t & 1];

        // QK^T (swapped): sacc[qf][fk], lane: q=l15, kv=fk*16+l4*4+r
        f32x4 sacc[2][4];
        #pragma unroll
        for (int qf = 0; qf < 2; ++qf)
            #pragma unroll
            for (int fk = 0; fk < 4; ++fk) sacc[qf][fk] = (f32x4){0.f, 0.f, 0.f, 0.f};

        __builtin_amdgcn_s_setprio(1);
        #pragma unroll
        for (int c = 0; c < 8; ++c) {
            short8 kf[4];
            #pragma unroll
            for (int fk = 0; fk < 4; ++fk) {
                int r = fk * 16 + l15;
                int ch = (4 * c + l4) ^ (r & 7);
                kf[fk] = *(const short8*)&Kb[r * 256 + ch * 8];
            }
            #pragma unroll
            for (int fk = 0; fk < 4; ++fk) {
                sacc[0][fk] = __builtin_amdgcn_mfma_f32_16x16x32_bf16(kf[fk], qreg[0][c], sacc[0][fk], 0, 0, 0);
                sacc[1][fk] = __builtin_amdgcn_mfma_f32_16x16x32_bf16(kf[fk], qreg[1][c], sacc[1][fk], 0, 0, 0);
            }
        }
        __builtin_amdgcn_s_setprio(0);

        // online softmax per q-frag; exp overwrites sacc in place (reg save)
        #pragma unroll
        for (int qf = 0; qf < 2; ++qf) {
            float tm = sacc[qf][0][0];
            #pragma unroll
            for (int fk = 0; fk < 4; ++fk)
                #pragma unroll
                for (int rr = 0; rr < 4; ++rr) tm = fmaxf(tm, sacc[qf][fk][rr]);
            tm = fmaxf(tm, __shfl_xor(tm, 16));
            tm = fmaxf(tm, __shfl_xor(tm, 32));

            // defer-max: rescale only when tile max exceeds running max + THR
            if (!__all(tm <= m_r[qf] + 5.545f)) {
                float mnew = fmaxf(m_r[qf], tm);
                float corr = __expf(m_r[qf] - mnew);
                float c4[4];
                #pragma unroll
                for (int r = 0; r < 4; ++r) c4[r] = __shfl(corr, l4 * 4 + r);
                #pragma unroll
                for (int dn = 0; dn < 16; ++dn)
                    #pragma unroll
                    for (int r = 0; r < 4; ++r) oacc[qf][dn][r] *= c4[r];
                l_r[qf] *= corr;
                m_r[qf] = mnew;
            }

            float ls = 0.f;
            #pragma unroll
            for (int fk = 0; fk < 4; ++fk)
                #pragma unroll
                for (int rr = 0; rr < 4; ++rr) {
                    float e = __expf(sacc[qf][fk][rr] - m_r[qf]);
                    sacc[qf][fk][rr] = e; ls += e;
                }
            ls += __shfl_xor(ls, 16);
            ls += __shfl_xor(ls, 32);
            l_r[qf] += ls;
        }

        // PV per 32-kv chunk: swizzled LDS repack -> A-frags, then MFMA
        #pragma unroll
        for (int kvc = 0; kvc < 2; ++kvc) {
            #pragma unroll
            for (int qf = 0; qf < 2; ++qf)
                #pragma unroll
                for (int fh = 0; fh < 2; ++fh) {
                    int fk = kvc * 2 + fh;
                    uint2 wv;
                    wv.x = cvt_pk_bf16(sacc[qf][fk][0], sacc[qf][fk][1]);
                    wv.y = cvt_pk_bf16(sacc[qf][fk][2], sacc[qf][fk][3]);
                    *(uint2*)&Pw[(qf * 16 + l15) * 32 + ((fh * 16 + l4 * 4) ^ pswz)] = wv;
                }
            short8 pa0 = *(const short8*)&Pw[l15 * 32 + ((l4 * 8) ^ pswz)];
            short8 pa1 = *(const short8*)&Pw[(16 + l15) * 32 + ((l4 * 8) ^ pswz)];

            __builtin_amdgcn_s_setprio(1);
            #pragma unroll
            for (int dn = 0; dn < 16; ++dn) {
                int row = dn * 16 + l15;
                int ch = (kvc * 4 + l4) ^ (row & 7);
                short8 vf = *(const short8*)&Vb[row * 64 + ch * 8];
                oacc[0][dn] = __builtin_amdgcn_mfma_f32_16x16x32_bf16(pa0, vf, oacc[0][dn], 0, 0, 0);
                oacc[1][dn] = __builtin_amdgcn_mfma_f32_16x16x32_bf16(pa1, vf, oacc[1][dn], 0, 0, 0);
            }
            __builtin_amdgcn_s_setprio(0);
        }
        __builtin_amdgcn_s_barrier();
    }

    // epilogue: store normalized O (bf16) + (m,l)
    unsigned short* Ob = Opart + (ull)(sp * 4 + h) * NTOK * 256;
    #pragma unroll
    for (int qf = 0; qf < 2; ++qf) {
        float inv = 1.f / l_r[qf];
        float c4[4];
        #pragma unroll
        for (int r = 0; r < 4; ++r) c4[r] = __shfl(inv, l4 * 4 + r);
        #pragma unroll
        for (int dn = 0; dn < 16; ++dn) {
            int d = dn * 16 + l15;
            #pragma unroll
            for (int r = 0; r < 4; ++r) {
                int q = qbase + qf * 16 + l4 * 4 + r;
                Ob[(ull)q * 256 + d] = f2bf(oacc[qf][dn][r] * c4[r]);
            }
        }
        if (l4 == 0) {
            float2* mlp = (float2*)ml + (ull)(sp * 4 + h) * NTOK + qbase + qf * 16 + l15;
            *mlp = make_float2(m_r[qf], l_r[qf]);
        }
    }
}

// ---------------------------------------------------------------------------
// merge 4 KV-split partials -> att split pair. block = one q row (4h x 256d).
__global__ __launch_bounds__(256)
void flash_combine(const unsigned short* __restrict__ Opart, const float* __restrict__ ml,
                   unsigned short* __restrict__ attH, unsigned short* __restrict__ attL)
{
    const int q = blockIdx.x;
    const int t = threadIdx.x;
    const int h = t >> 6, d4 = (t & 63) * 4;

    float2 m4[4]; float ms = -1e30f;
    #pragma unroll
    for (int s = 0; s < 4; ++s) {
        m4[s] = ((const float2*)ml)[(ull)(s * 4 + h) * NTOK + q];
        ms = fmaxf(ms, m4[s].x);
    }
    float wt[4], denom = 0.f;
    #pragma unroll
    for (int s = 0; s < 4; ++s) {
        wt[s] = __expf(m4[s].x - ms) * m4[s].y;
        denom += wt[s];
    }
    float inv = 1.f / denom;
    float acc[4] = { 0.f, 0.f, 0.f, 0.f };
    #pragma unroll
    for (int s = 0; s < 4; ++s) {
        ushort4 o = *(const ushort4*)&Opart[((ull)(s * 4 + h) * NTOK + q) * 256 + d4];
        acc[0] += wt[s] * bf2f(o.x); acc[1] += wt[s] * bf2f(o.y);
        acc[2] += wt[s] * bf2f(o.z); acc[3] += wt[s] * bf2f(o.w);
    }
    ull ai = (ull)q * EMB + h * 256 + d4;
    ushort4 ho, lo;
    float v0 = acc[0] * inv, v1 = acc[1] * inv, v2 = acc[2] * inv, v3 = acc[3] * inv;
    ho.x = f2bf(v0); lo.x = f2bf(v0 - bf2f(ho.x));
    ho.y = f2bf(v1); lo.y = f2bf(v1 - bf2f(ho.y));
    ho.z = f2bf(v2); lo.z = f2bf(v2 - bf2f(ho.z));
    ho.w = f2bf(v3); lo.w = f2bf(v3 - bf2f(ho.w));
    *(ushort4*)&attH[ai] = ho;
    *(ushort4*)&attL[ai] = lo;
}

// ---------------------------------------------------------------------------
template<bool F32IN>
__global__ __launch_bounds__(256)
void l2norm_rows(const float* __restrict__ inF, const unsigned short* __restrict__ inH,
                 const unsigned short* __restrict__ inL,
                 unsigned short* __restrict__ oH, unsigned short* __restrict__ oL)
{
    const ull row = blockIdx.x;
    const int t = threadIdx.x;
    const int lane = t & 63, wid = t >> 6;
    __shared__ float red[4];

    float v[4];
    if constexpr (F32IN) {
        float4 x = *(const float4*)&inF[row * EMB + t * 4];
        v[0] = x.x; v[1] = x.y; v[2] = x.z; v[3] = x.w;
    } else {
        ushort4 hh = *(const ushort4*)&inH[row * EMB + t * 4];
        ushort4 ll = *(const ushort4*)&inL[row * EMB + t * 4];
        v[0] = bf2f(hh.x) + bf2f(ll.x); v[1] = bf2f(hh.y) + bf2f(ll.y);
        v[2] = bf2f(hh.z) + bf2f(ll.z); v[3] = bf2f(hh.w) + bf2f(ll.w);
    }
    float ss = v[0] * v[0] + v[1] * v[1] + v[2] * v[2] + v[3] * v[3];
    #pragma unroll
    for (int o = 32; o > 0; o >>= 1) ss += __shfl_down(ss, o);
    if (lane == 0) red[wid] = ss;
    __syncthreads();
    ss = red[0] + red[1] + red[2] + red[3];

    float inv = 1.f / fmaxf(sqrtf(ss), 1e-8f);
    ushort4 ho, lo;
    float s0 = v[0] * inv, s1 = v[1] * inv, s2 = v[2] * inv, s3 = v[3] * inv;
    ho.x = f2bf(s0); lo.x = f2bf(s0 - bf2f(ho.x));
    ho.y = f2bf(s1); lo.y = f2bf(s1 - bf2f(ho.y));
    ho.z = f2bf(s2); lo.z = f2bf(s2 - bf2f(ho.z));
    ho.w = f2bf(s3); lo.w = f2bf(s3 - bf2f(ho.w));
    *(ushort4*)&oH[row * EMB + t * 4] = ho;
    *(ushort4*)&oL[row * EMB + t * 4] = lo;
}

__global__ __launch_bounds__(256)
void add_pos_pair(const float* __restrict__ in, const float* __restrict__ pos,
                  unsigned short* __restrict__ oH, unsigned short* __restrict__ oL)
{
    ull i = ((ull)blockIdx.x * 256 + threadIdx.x) * 4;
    float4 a = *(const float4*)&in[i];
    float4 p = *(const float4*)&pos[(int)(i & (EMB - 1))];
    float w[4] = { a.x + p.x, a.y + p.y, a.z + p.z, a.w + p.w };
    ushort4 ho, lo;
    ho.x = f2bf(w[0]); lo.x = f2bf(w[0] - bf2f(ho.x));
    ho.y = f2bf(w[1]); lo.y = f2bf(w[1] - bf2f(ho.y));
    ho.z = f2bf(w[2]); lo.z = f2bf(w[2] - bf2f(ho.z));
    ho.w = f2bf(w[3]); lo.w = f2bf(w[3] - bf2f(ho.w));
    *(ushort4*)&oH[i] = ho;
    *(ushort4*)&oL[i] = lo;
}

__global__ __launch_bounds__(256)
void split_pair(const float* __restrict__ in, unsigned short* __restrict__ oH,
                unsigned short* __restrict__ oL)
{
    ull i = ((ull)blockIdx.x * 256 + threadIdx.x) * 4;
    float4 a = *(const float4*)&in[i];
    float w[4] = { a.x, a.y, a.z, a.w };
    ushort4 ho, lo;
    ho.x = f2bf(w[0]); lo.x = f2bf(w[0] - bf2f(ho.x));
    ho.y = f2bf(w[1]); lo.y = f2bf(w[1] - bf2f(ho.y));
    ho.z = f2bf(w[2]); lo.z = f2bf(w[2] - bf2f(ho.z));
    ho.w = f2bf(w[3]); lo.w = f2bf(w[3] - bf2f(ho.w));
    *(ushort4*)&oH[i] = ho;
    *(ushort4*)&oL[i] = lo;
}

// transpose bf16 [4096][ld] block cols -> out [1024][4096]
__global__ __launch_bounds__(256)
void transpose_bf16(const unsigned short* __restrict__ in, int ld,
                    unsigned short* __restrict__ out) {
    __shared__ unsigned short tile[64][65];
    const int bx = blockIdx.x * 64;
    const int by = blockIdx.y * 64;
    const int t = threadIdx.x;
    #pragma unroll
    for (int i = 0; i < 16; ++i) {
        int idx = i * 256 + t;
        int r = idx >> 6, c = idx & 63;
        tile[r][c] = in[(ull)(by + r) * ld + bx + c];
    }
    __syncthreads();
    #pragma unroll
    for (int i = 0; i < 16; ++i) {
        int idx = i * 256 + t;
        int r = idx >> 6, c = idx & 63;
        out[(ull)(bx + r) * 4096 + by + c] = tile[c][r];
    }
}

// ---------------------------------------------------------------------------
namespace {

template<int S, int O>
inline void G(dim3 grid,
              const unsigned short* Ah, const unsigned short* Al, int lda, ull sAz,
              const unsigned short* Bh, const unsigned short* Bl, int ldb, ull sBz,
              void* Ch, void* Cl, int ldc, ull sCz,
              int K, float alpha, const float* bias,
              const unsigned short* rh, const unsigned short* rl, int rm, hipStream_t st)
{
    gemm_mfma<S, O><<<grid, dim3(256), 0, st>>>(Ah, Al, lda, sAz, Bh, Bl, ldb, sBz,
                                                Ch, Cl, ldc, sCz, K, alpha, bias, rh, rl, rm);
}

struct Bufs {
    unsigned short *Ph[6], *Pl[6];
    unsigned short *ATTh, *ATTl, *QKV, *VT, *Wih, *Wil, *Woh, *Wol, *Opart;
    float *ml;
};

void run_mha(const unsigned short* qh, const unsigned short* ql,
             const unsigned short* kh, const unsigned short* kl,
             const float* in_w, const float* in_b,
             const float* out_w, const float* out_b,
             unsigned short* dsth, unsigned short* dstl,
             const unsigned short* resh, const unsigned short* resl, int resMode,
             const Bufs& B, bool convW, hipStream_t s)
{
    const ull EE = (ull)EMB * EMB;
    if (convW) {
        split_pair<<<3 * EE / 1024, 256, 0, s>>>(in_w, B.Wih, B.Wil);
        split_pair<<<EE / 1024, 256, 0, s>>>(out_w, B.Woh, B.Wol);
    }
    // Q proj -> QKV[:, 0:1024]; fused KV proj -> QKV[:, 1024:3072]
    G<3, 1>(dim3(8, 32), qh, ql, EMB, 0, B.Wih, B.Wil, EMB, 0,
            B.QKV, nullptr, 3072, 0, EMB, 1.f, in_b, nullptr, nullptr, 0, s);
    G<3, 1>(dim3(16, 32), kh, kl, EMB, 0, B.Wih + EE, B.Wil + EE, EMB, 0,
            B.QKV + 1024, nullptr, 3072, 0, EMB, 1.f, in_b + EMB, nullptr, nullptr, 0, s);
    transpose_bf16<<<dim3(16, 64), 256, 0, s>>>(B.QKV + 2048, 3072, B.VT);

    flash_attn<<<dim3(16, 4, 4), 512, 0, s>>>(B.QKV, B.VT, B.Opart, B.ml);
    flash_combine<<<NTOK, 256, 0, s>>>(B.Opart, B.ml, B.ATTh, B.ATTl);

    G<3, 2>(dim3(EMB / 128, NTOK / 128), B.ATTh, B.ATTl, EMB, 0, B.Woh, B.Wol, EMB, 0,
            dsth, dstl, EMB, 0, EMB, 1.f, out_b, resh, resl, resMode, s);
}

} // namespace

extern "C" void kernel_launch(void* const* d_in, const int* in_sizes, int n_in,
                              void* d_out, int out_size, void* d_ws, size_t ws_size,
                              hipStream_t stream) {
    const float* local_feat  = (const float*)d_in[0];
    const float* global_feat = (const float*)d_in[1];
    const float* text_feat   = (const float*)d_in[2];
    const float* pos_l       = (const float*)d_in[3];
    const float* pos_g       = (const float*)d_in[4];
    const float* fc_w        = (const float*)d_in[5];
    const float* fc_b        = (const float*)d_in[6];
    const float* lg_in_w     = (const float*)d_in[7];
    const float* lg_in_b     = (const float*)d_in[8];
    const float* lg_out_w    = (const float*)d_in[9];
    const float* lg_out_b    = (const float*)d_in[10];
    const float* vt_in_w     = (const float*)d_in[11];
    const float* vt_in_b     = (const float*)d_in[12];
    const float* vt_out_w    = (const float*)d_in[13];
    const float* vt_out_b    = (const float*)d_in[14];
    const float* ml_in_w     = (const float*)d_in[15];
    const float* ml_in_b     = (const float*)d_in[16];
    const float* ml_out_w    = (const float*)d_in[17];
    const float* ml_out_b    = (const float*)d_in[18];
    float* out = (float*)d_out;

    const ull TE = (ull)NTOK * EMB;
    unsigned short* w = (unsigned short*)d_ws;
    Bufs B;
    for (int i = 0; i < 6; ++i) { B.Ph[i] = w + (2 * i) * TE; B.Pl[i] = w + (2 * i + 1) * TE; }
    B.ATTh = w + 12 * TE; B.ATTl = w + 13 * TE;
    B.QKV  = w + 14 * TE;               // 3 TE
    B.VT   = w + 17 * TE;               // 1 TE
    B.Opart = w + 18 * TE;              // 4 TE (bf16, 4 splits x 4 heads)
    B.ml    = (float*)(w + 22 * TE);    // 512 KB
    B.Wih = w + 26 * TE; B.Wil = B.Wih + 3 * (ull)EMB * EMB;
    B.Woh = B.Wil + 3 * (ull)EMB * EMB; B.Wol = B.Woh + (ull)EMB * EMB;

    add_pos_pair<<<TE / 1024, 256, 0, stream>>>(local_feat, pos_l, B.Ph[0], B.Pl[0]);
    add_pos_pair<<<TE / 1024, 256, 0, stream>>>(global_feat, pos_g, B.Ph[1], B.Pl[1]);

    // tf = text @ fc_w^T + fc_b -> P2 (text split staged in ATT pair)
    split_pair<<<TE / 1024, 256, 0, stream>>>(text_feat, B.ATTh, B.ATTl);
    split_pair<<<(ull)EMB * EMB / 1024, 256, 0, stream>>>(fc_w, B.Wih, B.Wil);
    G<3, 2>(dim3(EMB / 128, NTOK / 128), B.ATTh, B.ATTl, EMB, 0, B.Wih, B.Wil, EMB, 0,
            B.Ph[2], B.Pl[2], EMB, 0, EMB, 1.f, fc_b, nullptr, nullptr, 0, stream);

    run_mha(B.Ph[0], B.Pl[0], B.Ph[1], B.Pl[1], lg_in_w, lg_in_b, lg_out_w, lg_out_b,
            B.Ph[3], B.Pl[3], B.Ph[0], B.Pl[0], 1, B, true, stream);
    run_mha(B.Ph[2], B.Pl[2], B.Ph[0], B.Pl[0], vt_in_w, vt_in_b, vt_out_w, vt_out_b,
            B.Ph[4], B.Pl[4], B.Ph[0], B.Pl[0], 1, B, true, stream);
    run_mha(B.Ph[2], B.Pl[2], B.Ph[1], B.Pl[1], vt_in_w, vt_in_b, vt_out_w, vt_out_b,
            B.Ph[5], B.Pl[5], B.Ph[2], B.Pl[2], 1, B, false, stream);
    run_mha(B.Ph[3], B.Pl[3], B.Ph[5], B.Pl[5], ml_in_w, ml_in_b, ml_out_w, ml_out_b,
            B.Ph[0], B.Pl[0], nullptr, nullptr, 0, B, true, stream);
    run_mha(B.Ph[4], B.Pl[4], B.Ph[3], B.Pl[3], ml_in_w, ml_in_b, ml_out_w, ml_out_b,
            B.Ph[1], B.Pl[1], nullptr, nullptr, 0, B, false, stream);
    run_mha(B.Ph[1], B.Pl[1], B.Ph[0], B.Pl[0], ml_in_w, ml_in_b, ml_out_w, ml_out_b,
            B.Ph[3], B.Pl[3], nullptr, nullptr, 0, B, false, stream);
    run_mha(B.Ph[2], B.Pl[2], B.Ph[3], B.Pl[3], ml_in_w, ml_in_b, ml_out_w, ml_out_b,
            B.Ph[4], B.Pl[4], B.Ph[2], B.Pl[2], 2, B, false, stream);

    l2norm_rows<false><<<NTOK, 256, 0, stream>>>(nullptr, B.Ph[4], B.Pl[4], B.Ph[4], B.Pl[4]);
    l2norm_rows<true ><<<NTOK, 256, 0, stream>>>(local_feat, nullptr, nullptr, B.Ph[5], B.Pl[5]);

    G<3, 0>(dim3(QTY / 128, QTY / 128, 8),
            B.Ph[4], B.Pl[4], EMB, (ull)QTY * EMB,
            B.Ph[5], B.Pl[5], EMB, (ull)QTY * EMB,
            out, nullptr, QTY, (ull)QTY * QTY,
            EMB, 1.f, nullptr, nullptr, nullptr, 0, stream);
}